// Round 1
// baseline (135.205 us; speedup 1.0000x reference)
//
#include <hip/hip_runtime.h>

static constexpr int IMG = 512;
static constexpr int TX  = 64;             // tile width  (output)
static constexpr int TY  = 32;             // tile height (output)
static constexpr int LST = 72;             // staged row stride in floats (16B aligned, 4+64+4)
static constexpr int SROWS  = TY + 6;      // 38 staged rows (halo 3 each side)
static constexpr int NSTAGE = SROWS * (LST / 4);   // 684 float4 items

__device__ __forceinline__ float gd_acc(float d, float acc) {
    const float t    = fmaf(d, d, 1.0f);
    const float rinv = __builtin_amdgcn_rcpf(t);
    const float e    = __builtin_amdgcn_exp2f(
                           -1.442695040888963f * __builtin_fabsf(d) * rinv);
    return fmaf(e, d, acc);
}

// One diffusion step over the LDS tile. Column coordinate slides by the window
// offset each step so every LDS read stays 16B/8B aligned:
//   stage A col c  <-> gx = tx0-4+c ; after step1 Bs col c <-> gx = tx0-2+c ;
//   after step2 A col c <-> gx = tx0-1+c ; step3 writes gout at gx = tx0+c0+i.
template<int WOFF, int NR, int RLO, int NG, bool TO_GLOBAL>
__device__ __forceinline__ void diffuse_step(
    const float* __restrict__ prev, float* __restrict__ cur,
    const float* __restrict__ Wt, const float* __restrict__ bt,
    int xoff, int ty0, int tx0, int tid, float* __restrict__ gout)
{
    constexpr int NITEMS = NR * NG;
    for (int idx = tid; idx < NITEMS; idx += 256) {
        const int rr = idx / NG, j = idx - rr * NG;
        const int r  = RLO + rr, c0 = 4 * j;
        const float* base = prev + (r - 1) * LST + c0;

        float L0[8], L1[8], L2[8];
        *(float4*)&L0[0] = *(const float4*)(base);
        *(float4*)&L1[0] = *(const float4*)(base + LST);
        *(float4*)&L2[0] = *(const float4*)(base + 2 * LST);
        if (WOFF) {
            *(float4*)&L0[4] = *(const float4*)(base + 4);
            *(float4*)&L1[4] = *(const float4*)(base + LST + 4);
            *(float4*)&L2[4] = *(const float4*)(base + 2 * LST + 4);
        } else {
            *(float2*)&L0[4] = *(const float2*)(base + 4);
            *(float2*)&L1[4] = *(const float2*)(base + LST + 4);
            *(float2*)&L2[4] = *(const float2*)(base + 2 * LST + 4);
        }

        float acc[4] = {0.f, 0.f, 0.f, 0.f};
#pragma unroll
        for (int k = 0; k < 8; ++k) {
            const float w0 = Wt[9*k+0], w1 = Wt[9*k+1], w2 = Wt[9*k+2];
            const float w3 = Wt[9*k+3], w4 = Wt[9*k+4], w5 = Wt[9*k+5];
            const float w6 = Wt[9*k+6], w7 = Wt[9*k+7], w8 = Wt[9*k+8];
            const float bk = bt[k];
#pragma unroll
            for (int i = 0; i < 4; ++i) {
                float d = bk;
                d = fmaf(w0, L0[WOFF+i],   d);
                d = fmaf(w1, L0[WOFF+i+1], d);
                d = fmaf(w2, L0[WOFF+i+2], d);
                d = fmaf(w3, L1[WOFF+i],   d);
                d = fmaf(w4, L1[WOFF+i+1], d);
                d = fmaf(w5, L1[WOFF+i+2], d);
                d = fmaf(w6, L2[WOFF+i],   d);
                d = fmaf(w7, L2[WOFF+i+1], d);
                d = fmaf(w8, L2[WOFF+i+2], d);
                acc[i] = gd_acc(d, acc[i]);
            }
        }

        float4 v;
        v.x = L1[WOFF+1] - acc[0] * 0.125f;
        v.y = L1[WOFF+2] - acc[1] * 0.125f;
        v.z = L1[WOFF+3] - acc[2] * 0.125f;
        v.w = L1[WOFF+4] - acc[3] * 0.125f;

        const int gy = ty0 - 3 + r;
        if (TO_GLOBAL) {
            // step3: rows/cols are always fully interior to the image
            *(float4*)&gout[gy * IMG + tx0 + c0] = v;
        } else {
            // zero out-of-image pixels so the next step sees SAME zero padding
            const bool ry  = (unsigned)gy < (unsigned)IMG;
            const int  gx0 = xoff + c0;
            v.x = (ry && (unsigned)(gx0 + 0) < (unsigned)IMG) ? v.x : 0.f;
            v.y = (ry && (unsigned)(gx0 + 1) < (unsigned)IMG) ? v.y : 0.f;
            v.z = (ry && (unsigned)(gx0 + 2) < (unsigned)IMG) ? v.z : 0.f;
            v.w = (ry && (unsigned)(gx0 + 3) < (unsigned)IMG) ? v.w : 0.f;
            *(float4*)&cur[r * LST + c0] = v;
        }
    }
}

// All 3 diffusion steps fused: stage 38x72 input tile to LDS, ping-pong A<->B,
// write only the final 64x32 tile to HBM. 256 threads (4 waves) per block.
__global__ __launch_bounds__(256) void deep_ad_fused256(
    const float* __restrict__ x, const float* __restrict__ W,
    const float* __restrict__ b, float* __restrict__ out)
{
    __shared__ float A [SROWS * LST];
    __shared__ float Bs[SROWS * LST];

    const int tid = threadIdx.x;
    const int tx0 = blockIdx.x * TX;
    const int ty0 = blockIdx.y * TY;
    const float* xin  = x   + (size_t)blockIdx.z * (IMG * IMG);
    float*       gout = out + (size_t)blockIdx.z * (IMG * IMG);

    // ---- stage input tile (zeros outside image == SAME padding) ----
    {
        float4 sv[3];
#pragma unroll
        for (int q = 0; q < 3; ++q) {
            const int item = tid + 256 * q;
            float4 v = {0.f, 0.f, 0.f, 0.f};
            if (item < NSTAGE) {
                const int rr = item / 18, j = item - rr * 18;
                const int gy = ty0 - 3 + rr;
                const int gx = tx0 - 4 + 4 * j;   // float4 groups are fully in or out
                if ((unsigned)gy < (unsigned)IMG && (unsigned)gx < (unsigned)IMG)
                    v = *(const float4*)(xin + gy * IMG + gx);
            }
            sv[q] = v;
        }
#pragma unroll
        for (int q = 0; q < 3; ++q) {
            const int item = tid + 256 * q;
            if (item < NSTAGE) *(float4*)&A[item * 4] = sv[q];
        }
    }
    __syncthreads();

    // step1: rows 1..36, 17 col-groups; step2: rows 2..35; step3: rows 3..34 -> global
    diffuse_step<1, TY + 4, 1, 17, false>(A,  Bs, W,       b,      tx0 - 2, ty0, tx0, tid, nullptr);
    __syncthreads();
    diffuse_step<0, TY + 2, 2, 17, false>(Bs, A,  W + 72,  b + 8,  tx0 - 1, ty0, tx0, tid, nullptr);
    __syncthreads();
    diffuse_step<0, TY,     3, 16, true >(A, nullptr, W + 144, b + 16, 0, ty0, tx0, tid, gout);
}

extern "C" void kernel_launch(void* const* d_in, const int* in_sizes, int n_in,
                              void* d_out, int out_size, void* d_ws, size_t ws_size,
                              hipStream_t stream)
{
    const float* x = (const float*)d_in[0];
    const float* W = (const float*)d_in[1];  // [3,8,1,3,3]
    const float* b = (const float*)d_in[2];  // [3,8]
    float* out = (float*)d_out;
    const int N = in_sizes[0] / (IMG * IMG); // 16

    dim3 grid(IMG / TX, IMG / TY, N);        // (8, 16, 16) = 2048 blocks
    deep_ad_fused256<<<grid, 256, 0, stream>>>(x, W, b, out);
}